// Round 1
// 1136.489 us; speedup vs baseline: 3.0795x; 3.0795x over previous
//
#include <hip/hip_runtime.h>

// GumbelCodebook: B=32, N=64, D=256, C=8192 — ALL I/O fp32.
// Outputs concatenated in d_out (float): quantized[B*N*D] | log_alpha[B*N*C] | z[B*N*C]
//
// Round 3: kill the scalar-load latency disease. Every GEMM-ish kernel previously
// fetched its block-uniform operand (z / logits / qp rows) from global memory inside
// the FMA loop as s_load (4% VALUBusy, 0.9% HBM on k_codebook). Now:
//   - stage the block-uniform operand ONCE per block into LDS (coalesced float4),
//   - inner loop reads it as ds_read_b128 broadcast (same-address -> conflict-free),
//   - streamed operand (head/wt/pos_map) stays coalesced global vector loads.
// Per 4-k group: 4 global loads + 32 LDS b128 broadcasts + 128 FMAs.
//
// ws layout (floats): qp[524288] | wt[2097152]  (10.5 MB)

#define B_ 32
#define N_ 64
#define D_ 256
#define C_ 8192

__global__ __launch_bounds__(256) void k_zero(float* __restrict__ qp) {
    qp[blockIdx.x * 256 + threadIdx.x] = 0.0f;   // grid covers exactly B*N*D
}

__global__ __launch_bounds__(256) void k_transpose(const float* __restrict__ w,
                                                   float* __restrict__ wt) {
    // w: [D][C] -> wt: [C][D]. 64x64 tiles, LDS padded +1.
    __shared__ float t[64][65];
    const int c0 = blockIdx.x * 64;
    const int d0 = blockIdx.y * 64;
    const int col = threadIdx.x & 63;
    const int rbase = threadIdx.x >> 6;   // 0..3
#pragma unroll
    for (int i = 0; i < 16; i++) {
        int r = rbase + i * 4;            // d offset within tile
        t[r][col] = w[(size_t)(d0 + r) * C_ + (c0 + col)];
    }
    __syncthreads();
#pragma unroll
    for (int i = 0; i < 16; i++) {
        int r = rbase + i * 4;            // c offset within tile
        wt[(size_t)(c0 + r) * D_ + (d0 + col)] = t[col][r];
    }
}

// log_alpha[b][n][c] = sum_d logits[b][n][d] * head[n][d][c]
// grid: (32 c-chunks, 64 n). 256 threads = 256 c's. logits[32][256] staged in LDS (32KB).
// head (512 MB) read exactly once, coalesced. Memory-bound floor ~91us.
__global__ __launch_bounds__(256) void k_logalpha(const float* __restrict__ logits,
                                                  const float* __restrict__ head,
                                                  float* __restrict__ out_la) {
    const int n = blockIdx.y;
    const int t = threadIdx.x;
    const int c = blockIdx.x * 256 + t;

    __shared__ float4 ls4[B_ * 64];               // logits[32][256] as float4 [32][64]
    const float4* lg4 = (const float4*)logits;
#pragma unroll
    for (int i = 0; i < 8; i++) {
        int f = i * 256 + t;                      // 0..2047
        int b = f >> 6, d4 = f & 63;
        ls4[f] = lg4[(size_t)(b * N_ + n) * 64 + d4];   // coalesced 16B/lane
    }
    __syncthreads();

    float acc[B_];
#pragma unroll
    for (int b = 0; b < B_; b++) acc[b] = 0.0f;

    const float* hp = head + (size_t)n * D_ * C_ + c;
#pragma unroll 2
    for (int g = 0; g < 64; g++) {                // 4 d's per iteration
        float h0 = hp[(size_t)(4 * g + 0) * C_];  // coalesced, streamed once
        float h1 = hp[(size_t)(4 * g + 1) * C_];
        float h2 = hp[(size_t)(4 * g + 2) * C_];
        float h3 = hp[(size_t)(4 * g + 3) * C_];
#pragma unroll
        for (int b = 0; b < B_; b++) {
            float4 lv = ls4[b * 64 + g];          // b128 broadcast, conflict-free
            acc[b] += lv.x * h0 + lv.y * h1 + lv.z * h2 + lv.w * h3;
        }
    }
#pragma unroll
    for (int b = 0; b < B_; b++)
        out_la[(size_t)(b * N_ + n) * C_ + c] = acc[b];
}

__global__ __launch_bounds__(256) void k_softmax(const float* __restrict__ la,
                                                 const float* __restrict__ gumbel,
                                                 const float* __restrict__ tau,
                                                 float* __restrict__ out_z) {
    const int row = blockIdx.x;             // b*N + n, 0..2047
    const int t = threadIdx.x;
    const float inv_tau = 1.0f / tau[0];

    const float4* lap = (const float4*)(la + (size_t)row * C_);
    const float4* gp  = (const float4*)(gumbel + (size_t)row * C_);
    float4* zp        = (float4*)(out_z + (size_t)row * C_);

    float4 s[8];
    float m = -1e30f;
#pragma unroll
    for (int i = 0; i < 8; i++) {
        int f = t + i * 256;                // float4 index, coalesced dwordx4
        float4 a = lap[f];
        float4 g = gp[f];
        float4 v;
        v.x = (a.x + g.x) * inv_tau;
        v.y = (a.y + g.y) * inv_tau;
        v.z = (a.z + g.z) * inv_tau;
        v.w = (a.w + g.w) * inv_tau;
        s[i] = v;
        m = fmaxf(m, fmaxf(fmaxf(v.x, v.y), fmaxf(v.z, v.w)));
    }

    __shared__ float red[8];
#pragma unroll
    for (int off = 32; off > 0; off >>= 1) m = fmaxf(m, __shfl_down(m, off));
    if ((t & 63) == 0) red[t >> 6] = m;
    __syncthreads();
    if (t == 0) red[4] = fmaxf(fmaxf(red[0], red[1]), fmaxf(red[2], red[3]));
    __syncthreads();
    m = red[4];

    float sum = 0.0f;
#pragma unroll
    for (int i = 0; i < 8; i++) {
        float4 v = s[i];
        v.x = __expf(v.x - m);
        v.y = __expf(v.y - m);
        v.z = __expf(v.z - m);
        v.w = __expf(v.w - m);
        s[i] = v;
        sum += (v.x + v.y) + (v.z + v.w);
    }
#pragma unroll
    for (int off = 32; off > 0; off >>= 1) sum += __shfl_down(sum, off);
    __syncthreads();                        // all reads of red[4] (max) done
    if ((t & 63) == 0) red[t >> 6] = sum;
    __syncthreads();
    if (t == 0) red[4] = red[0] + red[1] + red[2] + red[3];
    __syncthreads();
    const float inv = 1.0f / red[4];

#pragma unroll
    for (int i = 0; i < 8; i++) {
        float4 v = s[i];
        v.x *= inv; v.y *= inv; v.z *= inv; v.w *= inv;
        zp[t + i * 256] = v;                // coalesced dwordx4
    }
}

// qp[b][n][d] += sum_{c in chunk} z[b][n][c] * wt[c][d]
// grid: 32 chunks x 64 n = 2048 blocks. 256 threads = 256 d's.
// z[32][256] chunk staged in LDS (32KB) -> broadcast reads. wt L2/L3-resident.
__global__ __launch_bounds__(256) void k_codebook(const float* __restrict__ z,
                                                  const float* __restrict__ wt,
                                                  float* __restrict__ qp) {
    const int n = blockIdx.x & 63;
    const int chunk = blockIdx.x >> 6;      // 0..31, 256 c each
    const int d = threadIdx.x;
    const int c0 = chunk * 256;

    __shared__ float4 zs4[B_ * 64];         // z[32][256] as float4 [32][64]
    const float4* z4 = (const float4*)z;
#pragma unroll
    for (int i = 0; i < 8; i++) {
        int f = i * 256 + d;                // 0..2047
        int b = f >> 6, c4 = f & 63;
        zs4[f] = z4[(size_t)(b * N_ + n) * (C_ / 4) + (c0 >> 2) + c4];
    }
    __syncthreads();

    float acc[B_];
#pragma unroll
    for (int b = 0; b < B_; b++) acc[b] = 0.0f;

    const float* wp = wt + (size_t)c0 * D_ + d;
#pragma unroll 2
    for (int g = 0; g < 64; g++) {          // 4 c's per iteration
        float w0 = wp[(4 * g + 0) * D_];    // coalesced, L2/L3-resident (8 MB)
        float w1 = wp[(4 * g + 1) * D_];
        float w2 = wp[(4 * g + 2) * D_];
        float w3 = wp[(4 * g + 3) * D_];
#pragma unroll
        for (int b = 0; b < B_; b++) {
            float4 zv = zs4[b * 64 + g];    // b128 broadcast, conflict-free
            acc[b] += zv.x * w0 + zv.y * w1 + zv.z * w2 + zv.w * w3;
        }
    }
#pragma unroll
    for (int b = 0; b < B_; b++) {
        atomicAdd(&qp[(b * N_ + n) * D_ + d], acc[b]);   // 32 adds/address
    }
}

// quantized[b][n][m] = sum_d qp[b][n][d] * pos_map[n][d][m]
// grid: 4 b-groups x 64 n = 256 blocks. qp rows (8KB) staged in LDS.
__global__ __launch_bounds__(256) void k_posmap(const float* __restrict__ qp,
                                                const float* __restrict__ pm,
                                                float* __restrict__ out_q) {
    const int n = blockIdx.x & 63;
    const int bg = blockIdx.x >> 6;         // 0..3, 8 b's each
    const int m = threadIdx.x;

    __shared__ float4 qs4[8 * 64];          // qp[8][256] as float4 [8][64]
    const float4* q4 = (const float4*)qp;
#pragma unroll
    for (int i = 0; i < 2; i++) {
        int f = i * 256 + m;                // 0..511
        int r = f >> 6, d4 = f & 63;
        qs4[f] = q4[(size_t)((bg * 8 + r) * N_ + n) * 64 + d4];
    }
    __syncthreads();

    float acc[8];
#pragma unroll
    for (int r = 0; r < 8; r++) acc[r] = 0.0f;

    const float* pp = pm + (size_t)n * D_ * D_ + m;
#pragma unroll 2
    for (int g = 0; g < 64; g++) {          // 4 d's per iteration
        float p0 = pp[(4 * g + 0) * D_];    // coalesced
        float p1 = pp[(4 * g + 1) * D_];
        float p2 = pp[(4 * g + 2) * D_];
        float p3 = pp[(4 * g + 3) * D_];
#pragma unroll
        for (int r = 0; r < 8; r++) {
            float4 qv = qs4[r * 64 + g];    // b128 broadcast
            acc[r] += qv.x * p0 + qv.y * p1 + qv.z * p2 + qv.w * p3;
        }
    }
#pragma unroll
    for (int r = 0; r < 8; r++)
        out_q[(size_t)((bg * 8 + r) * N_ + n) * D_ + m] = acc[r];
}

extern "C" void kernel_launch(void* const* d_in, const int* in_sizes, int n_in,
                              void* d_out, int out_size, void* d_ws, size_t ws_size,
                              hipStream_t stream) {
    const float* logits   = (const float*)d_in[0];
    const float* head     = (const float*)d_in[1];
    const float* pos_map  = (const float*)d_in[2];
    const float* codebook = (const float*)d_in[3];
    const float* gumbel   = (const float*)d_in[4];
    const float* tau      = (const float*)d_in[5];

    float* out    = (float*)d_out;
    float* out_q  = out;                                  // [B,N,D]
    float* out_la = out + (size_t)B_ * N_ * D_;           // [B,N,C]
    float* out_z  = out_la + (size_t)B_ * N_ * C_;        // [B,N,C]

    float* ws = (float*)d_ws;
    float* qp = ws;                          // 524288 floats
    float* wt = ws + 524288;                 // 2097152 floats (10.5 MB total)

    k_zero<<<2048, 256, 0, stream>>>(qp);
    {
        dim3 g(C_ / 64, D_ / 64);
        k_transpose<<<g, 256, 0, stream>>>(codebook, wt);
    }
    {
        dim3 g(C_ / 256, N_);
        k_logalpha<<<g, 256, 0, stream>>>(logits, head, out_la);
    }
    k_softmax<<<B_ * N_, 256, 0, stream>>>(out_la, gumbel, tau, out_z);
    k_codebook<<<32 * N_, 256, 0, stream>>>(out_z, wt, qp);
    k_posmap<<<4 * N_, 256, 0, stream>>>(qp, pos_map, out_q);
}

// Round 2
// 1099.572 us; speedup vs baseline: 3.1829x; 1.0336x over previous
//
#include <hip/hip_runtime.h>

// GumbelCodebook: B=32, N=64, D=256, C=8192 — ALL I/O fp32.
// Outputs concatenated in d_out (float): quantized[B*N*D] | log_alpha[B*N*C] | z[B*N*C]
//
// Round 4: register-block the streamed operand. Round 3 made the GEMM kernels
// LDS-broadcast-issue-bound (32 ds_read_b128 per 128 FMAs = 4 FMA/read; LDS port
// cost ~2x the FMA pipe per CU). Now each thread owns TWO output columns, so each
// LDS broadcast feeds 8 FMAs:
//   k_logalpha : thread owns c and c+256 (block = 512 c's)
//   k_codebook : thread owns adjacent d pair (float2 wt loads), chunk split in halves
//   k_posmap   : thread owns adjacent m pair (float2 pm loads), 4 of 8 b-rows
// softmax/transpose/zero are at their memory floors already.
//
// ws layout (floats): qp[524288] | wt[2097152]  (10.5 MB)

#define B_ 32
#define N_ 64
#define D_ 256
#define C_ 8192

__global__ __launch_bounds__(256) void k_zero(float* __restrict__ qp) {
    qp[blockIdx.x * 256 + threadIdx.x] = 0.0f;   // grid covers exactly B*N*D
}

__global__ __launch_bounds__(256) void k_transpose(const float* __restrict__ w,
                                                   float* __restrict__ wt) {
    // w: [D][C] -> wt: [C][D]. 64x64 tiles, LDS padded +1.
    __shared__ float t[64][65];
    const int c0 = blockIdx.x * 64;
    const int d0 = blockIdx.y * 64;
    const int col = threadIdx.x & 63;
    const int rbase = threadIdx.x >> 6;   // 0..3
#pragma unroll
    for (int i = 0; i < 16; i++) {
        int r = rbase + i * 4;            // d offset within tile
        t[r][col] = w[(size_t)(d0 + r) * C_ + (c0 + col)];
    }
    __syncthreads();
#pragma unroll
    for (int i = 0; i < 16; i++) {
        int r = rbase + i * 4;            // c offset within tile
        wt[(size_t)(c0 + r) * D_ + (d0 + col)] = t[col][r];
    }
}

// log_alpha[b][n][c] = sum_d logits[b][n][d] * head[n][d][c]
// grid: (16 c-chunks of 512, 64 n). Thread owns c and c+256 -> each LDS broadcast
// feeds 8 FMAs. head (512 MB) streamed once, coalesced. Floor ~85us.
__global__ __launch_bounds__(256) void k_logalpha(const float* __restrict__ logits,
                                                  const float* __restrict__ head,
                                                  float* __restrict__ out_la) {
    const int n = blockIdx.y;
    const int t = threadIdx.x;
    const int c = blockIdx.x * 512 + t;

    __shared__ float4 ls4[B_ * 64];               // logits[32][256] as float4 [32][64]
    const float4* lg4 = (const float4*)logits;
#pragma unroll
    for (int i = 0; i < 8; i++) {
        int f = i * 256 + t;                      // 0..2047
        int b = f >> 6, d4 = f & 63;
        ls4[f] = lg4[(size_t)(b * N_ + n) * 64 + d4];   // coalesced 16B/lane
    }
    __syncthreads();

    float acc0[B_], acc1[B_];
#pragma unroll
    for (int b = 0; b < B_; b++) { acc0[b] = 0.0f; acc1[b] = 0.0f; }

    const float* hp0 = head + (size_t)n * D_ * C_ + c;
    const float* hp1 = hp0 + 256;
#pragma unroll 2
    for (int g = 0; g < 64; g++) {                // 4 d's per iteration
        float h00 = hp0[(size_t)(4 * g + 0) * C_];   // coalesced, streamed once
        float h01 = hp0[(size_t)(4 * g + 1) * C_];
        float h02 = hp0[(size_t)(4 * g + 2) * C_];
        float h03 = hp0[(size_t)(4 * g + 3) * C_];
        float h10 = hp1[(size_t)(4 * g + 0) * C_];
        float h11 = hp1[(size_t)(4 * g + 1) * C_];
        float h12 = hp1[(size_t)(4 * g + 2) * C_];
        float h13 = hp1[(size_t)(4 * g + 3) * C_];
#pragma unroll
        for (int b = 0; b < B_; b++) {
            float4 lv = ls4[b * 64 + g];          // b128 broadcast -> 8 FMAs
            acc0[b] += lv.x * h00 + lv.y * h01 + lv.z * h02 + lv.w * h03;
            acc1[b] += lv.x * h10 + lv.y * h11 + lv.z * h12 + lv.w * h13;
        }
    }
#pragma unroll
    for (int b = 0; b < B_; b++) {
        out_la[(size_t)(b * N_ + n) * C_ + c]       = acc0[b];
        out_la[(size_t)(b * N_ + n) * C_ + c + 256] = acc1[b];
    }
}

__global__ __launch_bounds__(256) void k_softmax(const float* __restrict__ la,
                                                 const float* __restrict__ gumbel,
                                                 const float* __restrict__ tau,
                                                 float* __restrict__ out_z) {
    const int row = blockIdx.x;             // b*N + n, 0..2047
    const int t = threadIdx.x;
    const float inv_tau = 1.0f / tau[0];

    const float4* lap = (const float4*)(la + (size_t)row * C_);
    const float4* gp  = (const float4*)(gumbel + (size_t)row * C_);
    float4* zp        = (float4*)(out_z + (size_t)row * C_);

    float4 s[8];
    float m = -1e30f;
#pragma unroll
    for (int i = 0; i < 8; i++) {
        int f = t + i * 256;                // float4 index, coalesced dwordx4
        float4 a = lap[f];
        float4 g = gp[f];
        float4 v;
        v.x = (a.x + g.x) * inv_tau;
        v.y = (a.y + g.y) * inv_tau;
        v.z = (a.z + g.z) * inv_tau;
        v.w = (a.w + g.w) * inv_tau;
        s[i] = v;
        m = fmaxf(m, fmaxf(fmaxf(v.x, v.y), fmaxf(v.z, v.w)));
    }

    __shared__ float red[8];
#pragma unroll
    for (int off = 32; off > 0; off >>= 1) m = fmaxf(m, __shfl_down(m, off));
    if ((t & 63) == 0) red[t >> 6] = m;
    __syncthreads();
    if (t == 0) red[4] = fmaxf(fmaxf(red[0], red[1]), fmaxf(red[2], red[3]));
    __syncthreads();
    m = red[4];

    float sum = 0.0f;
#pragma unroll
    for (int i = 0; i < 8; i++) {
        float4 v = s[i];
        v.x = __expf(v.x - m);
        v.y = __expf(v.y - m);
        v.z = __expf(v.z - m);
        v.w = __expf(v.w - m);
        s[i] = v;
        sum += (v.x + v.y) + (v.z + v.w);
    }
#pragma unroll
    for (int off = 32; off > 0; off >>= 1) sum += __shfl_down(sum, off);
    __syncthreads();                        // all reads of red[4] (max) done
    if ((t & 63) == 0) red[t >> 6] = sum;
    __syncthreads();
    if (t == 0) red[4] = red[0] + red[1] + red[2] + red[3];
    __syncthreads();
    const float inv = 1.0f / red[4];

#pragma unroll
    for (int i = 0; i < 8; i++) {
        float4 v = s[i];
        v.x *= inv; v.y *= inv; v.z *= inv; v.w *= inv;
        zp[t + i * 256] = v;                // coalesced dwordx4
    }
}

// qp[b][n][d] += sum_{c in chunk} z[b][n][c] * wt[c][d]
// grid: 32 chunks x 64 n = 2048 blocks. Thread t: dsub = t&127 -> owns d = 2*dsub,
// 2*dsub+1 (float2 wt loads, coalesced); h = t>>7 -> processes half the 256-c chunk.
// Each LDS broadcast feeds 8 FMAs. wt L2/L3-resident.
__global__ __launch_bounds__(256) void k_codebook(const float* __restrict__ z,
                                                  const float* __restrict__ wt,
                                                  float* __restrict__ qp) {
    const int n = blockIdx.x & 63;
    const int chunk = blockIdx.x >> 6;      // 0..31, 256 c each
    const int t = threadIdx.x;
    const int dsub = t & 127;               // d pair index
    const int h = t >> 7;                   // which 128-c half of the chunk
    const int c0 = chunk * 256;

    __shared__ float4 zs4[B_ * 64];         // z[32][256] chunk as float4 [32][64]
    const float4* z4 = (const float4*)z;
#pragma unroll
    for (int i = 0; i < 8; i++) {
        int f = i * 256 + t;                // 0..2047
        int b = f >> 6, c4 = f & 63;
        zs4[f] = z4[(size_t)(b * N_ + n) * (C_ / 4) + (c0 >> 2) + c4];
    }
    __syncthreads();

    float acc0[B_], acc1[B_];
#pragma unroll
    for (int b = 0; b < B_; b++) { acc0[b] = 0.0f; acc1[b] = 0.0f; }

    // this thread's 128 c's: [c0 + h*128, c0 + h*128 + 128)
    const float2* wp = (const float2*)(wt + (size_t)(c0 + h * 128) * D_ + 2 * dsub);
#pragma unroll 2
    for (int g = 0; g < 32; g++) {          // 4 c's per iteration
        float2 w0 = wp[(4 * g + 0) * (D_ / 2)];   // coalesced 8B/lane, L2-resident
        float2 w1 = wp[(4 * g + 1) * (D_ / 2)];
        float2 w2 = wp[(4 * g + 2) * (D_ / 2)];
        float2 w3 = wp[(4 * g + 3) * (D_ / 2)];
        const int zi = h * 32 + g;          // float4 index within chunk row
#pragma unroll
        for (int b = 0; b < B_; b++) {
            float4 zv = zs4[b * 64 + zi];   // b128 broadcast -> 8 FMAs
            acc0[b] += zv.x * w0.x + zv.y * w1.x + zv.z * w2.x + zv.w * w3.x;
            acc1[b] += zv.x * w0.y + zv.y * w1.y + zv.z * w2.y + zv.w * w3.y;
        }
    }
    const int d0 = 2 * dsub;
#pragma unroll
    for (int b = 0; b < B_; b++) {
        atomicAdd(&qp[(b * N_ + n) * D_ + d0],     acc0[b]);   // 64 adds/address
        atomicAdd(&qp[(b * N_ + n) * D_ + d0 + 1], acc1[b]);
    }
}

// quantized[b][n][m] = sum_d qp[b][n][d] * pos_map[n][d][m]
// grid: 4 b-groups x 64 n = 256 blocks. Thread t: msub = t&127 -> m pair
// (float2 pm loads), rh = t>>7 -> 4 of the block's 8 b-rows. 8 FMAs per broadcast.
__global__ __launch_bounds__(256) void k_posmap(const float* __restrict__ qp,
                                                const float* __restrict__ pm,
                                                float* __restrict__ out_q) {
    const int n = blockIdx.x & 63;
    const int bg = blockIdx.x >> 6;         // 0..3, 8 b's each
    const int t = threadIdx.x;
    const int msub = t & 127;
    const int rh = t >> 7;                  // which 4 of the 8 rows

    __shared__ float4 qs4[8 * 64];          // qp[8][256] as float4 [8][64]
    const float4* q4 = (const float4*)qp;
#pragma unroll
    for (int i = 0; i < 2; i++) {
        int f = i * 256 + t;                // 0..511
        int r = f >> 6, d4 = f & 63;
        qs4[f] = q4[(size_t)((bg * 8 + r) * N_ + n) * 64 + d4];
    }
    __syncthreads();

    float acc0[4], acc1[4];
#pragma unroll
    for (int r = 0; r < 4; r++) { acc0[r] = 0.0f; acc1[r] = 0.0f; }

    const float2* pp = (const float2*)(pm + (size_t)n * D_ * D_ + 2 * msub);
#pragma unroll 2
    for (int g = 0; g < 64; g++) {          // 4 d's per iteration
        float2 p0 = pp[(4 * g + 0) * (D_ / 2)];   // coalesced 8B/lane
        float2 p1 = pp[(4 * g + 1) * (D_ / 2)];
        float2 p2 = pp[(4 * g + 2) * (D_ / 2)];
        float2 p3 = pp[(4 * g + 3) * (D_ / 2)];
#pragma unroll
        for (int r = 0; r < 4; r++) {
            float4 qv = qs4[(rh * 4 + r) * 64 + g];   // b128 broadcast -> 8 FMAs
            acc0[r] += qv.x * p0.x + qv.y * p1.x + qv.z * p2.x + qv.w * p3.x;
            acc1[r] += qv.x * p0.y + qv.y * p1.y + qv.z * p2.y + qv.w * p3.y;
        }
    }
#pragma unroll
    for (int r = 0; r < 4; r++) {
        float2 o; o.x = acc0[r]; o.y = acc1[r];
        *(float2*)(out_q + (size_t)((bg * 8 + rh * 4 + r) * N_ + n) * D_ + 2 * msub) = o;
    }
}

extern "C" void kernel_launch(void* const* d_in, const int* in_sizes, int n_in,
                              void* d_out, int out_size, void* d_ws, size_t ws_size,
                              hipStream_t stream) {
    const float* logits   = (const float*)d_in[0];
    const float* head     = (const float*)d_in[1];
    const float* pos_map  = (const float*)d_in[2];
    const float* codebook = (const float*)d_in[3];
    const float* gumbel   = (const float*)d_in[4];
    const float* tau      = (const float*)d_in[5];

    float* out    = (float*)d_out;
    float* out_q  = out;                                  // [B,N,D]
    float* out_la = out + (size_t)B_ * N_ * D_;           // [B,N,C]
    float* out_z  = out_la + (size_t)B_ * N_ * C_;        // [B,N,C]

    float* ws = (float*)d_ws;
    float* qp = ws;                          // 524288 floats
    float* wt = ws + 524288;                 // 2097152 floats (10.5 MB total)

    k_zero<<<2048, 256, 0, stream>>>(qp);
    {
        dim3 g(C_ / 64, D_ / 64);
        k_transpose<<<g, 256, 0, stream>>>(codebook, wt);
    }
    {
        dim3 g(C_ / 512, N_);
        k_logalpha<<<g, 256, 0, stream>>>(logits, head, out_la);
    }
    k_softmax<<<B_ * N_, 256, 0, stream>>>(out_la, gumbel, tau, out_z);
    k_codebook<<<32 * N_, 256, 0, stream>>>(out_z, wt, qp);
    k_posmap<<<4 * N_, 256, 0, stream>>>(qp, pos_map, out_q);
}